// Round 4
// baseline (155.922 us; speedup 1.0000x reference)
//
#include <hip/hip_runtime.h>

#define N_PTS 8192
#define BATCH 2
#define KNN 8
#define NBLK_C 1024                // chamfer: 4 combos x 256 row-blocks (32 rows)
#define NBLK_S 1024                // smooth: 2 batches x 512 (16 points)

// packed workspace layout: float4(x,y,z,|p|^2) per point
//  arr 0,1: pc2[b]            (chamfer candidates dir0 / rows dir1)
//  arr 2,3: pc1[b]+flow[b]    (warped: rows dir0 / candidates dir1)
//  arr 4,5: pc1[b]            (smooth rows+candidates)
// total 6*8192*16B = 768 KiB in d_ws
#define ARR_PC2  0
#define ARR_WARP 2
#define ARR_PC1  4

// ---------------- helpers ----------------
__device__ __forceinline__ void ce(unsigned &x, unsigned &y) {
    unsigned lo = min(x, y), hi = max(x, y); x = lo; y = hi;
}

__device__ __forceinline__ void insert4(unsigned o[4], unsigned key) {
    unsigned n0 = min(o[0], key);
    unsigned n1 = max(o[0], min(o[1], key));
    unsigned n2 = max(o[1], min(o[2], key));
    unsigned n3 = max(o[2], min(o[3], key));
    o[0]=n0; o[1]=n1; o[2]=n2; o[3]=n3;
}

__device__ __forceinline__ void merge_stage8(unsigned m[8], int d) {
    unsigned p[8], c[8];
    #pragma unroll
    for (int k = 0; k < 8; ++k) p[k] = (unsigned)__shfl_xor((int)m[k], d, 64);
    #pragma unroll
    for (int k = 0; k < 8; ++k) c[k] = min(m[k], p[7-k]);
    ce(c[0],c[4]); ce(c[1],c[5]); ce(c[2],c[6]); ce(c[3],c[7]);
    ce(c[0],c[2]); ce(c[1],c[3]); ce(c[4],c[6]); ce(c[5],c[7]);
    ce(c[0],c[1]); ce(c[2],c[3]); ce(c[4],c[5]); ce(c[6],c[7]);
    #pragma unroll
    for (int k = 0; k < 8; ++k) m[k] = c[k];
}

__device__ __forceinline__ void merge64(unsigned m[8]) {
    merge_stage8(m, 1); merge_stage8(m, 2); merge_stage8(m, 4);
    merge_stage8(m, 8); merge_stage8(m, 16); merge_stage8(m, 32);
}

// ---------------- pack: 6 float4 arrays, one-time warp-add + |p|^2 ----------------
__global__ __launch_bounds__(256) void pack_kernel(
        const float* __restrict__ pc1, const float* __restrict__ pc2,
        const float* __restrict__ flow, float4* __restrict__ ws) {
    const int t = blockIdx.x * 256 + threadIdx.x;   // 0 .. 6*8192-1
    const int arr = t >> 13, i = t & (N_PTS - 1);
    const int bb = arr & 1;
    const size_t base = (size_t)bb * N_PTS * 3 + (size_t)i * 3;
    float x, y, z;
    if (arr < 2)      { x = pc2[base+0];              y = pc2[base+1];              z = pc2[base+2]; }
    else if (arr < 4) { x = pc1[base+0] + flow[base+0];
                        y = pc1[base+1] + flow[base+1];
                        z = pc1[base+2] + flow[base+2]; }
    else              { x = pc1[base+0];              y = pc1[base+1];              z = pc1[base+2]; }
    ws[t] = make_float4(x, y, z, fmaf(x, x, fmaf(y, y, z * z)));
}

// ---------------- chamfer: barrier-free full scan, 32 rows/block (8/thread) ----------------
// R3 post-mortem: LDS-tile version was NOT DS-bound (4x DS cut = no change)
// and NOT inner-loop-VALU-bound (min3 pairing = no change). Remaining model:
// barrier-serialized staging latency (16 syncthreads/block, ~200cyc L2 loads
// inside the barrier window). This version has ZERO barriers in the scan:
// candidates stream from the packed L2-resident arrays as coalesced dwordx4,
// one load per 8 rows x 2 slabs, fully pipelineable.
__global__ __launch_bounds__(256, 4) void chamfer_kernel(
        const float4* __restrict__ ws, float* __restrict__ out) {
    __shared__ float psum[4];
    const int tid = threadIdx.x, bx = blockIdx.x;
    const int lane = tid & 63, wv = tid >> 6;
    const int z = bx >> 8, bb = z & 1, dir = z >> 1;
    const int cb = bx & 255;
    const float4* rows = ws + (size_t)((dir == 0 ? ARR_WARP : ARR_PC2) + bb) * N_PTS;
    const float4* cand = ws + (size_t)((dir == 0 ? ARR_PC2 : ARR_WARP) + bb) * N_PTS;
    const int rbase = cb * 32 + wv * 8;      // wave-uniform 8-row group

    float mx[8], my[8], mz[8], bmin[8];
    #pragma unroll
    for (int k = 0; k < 8; ++k) {
        float4 q = rows[rbase + k];          // wave-uniform -> broadcast load
        mx[k] = -2.0f * q.x; my[k] = -2.0f * q.y; mz[k] = -2.0f * q.z;
        bmin[k] = __builtin_inff();
    }

    // 64 paired iters: 2 dwordx4 feed 32 evals (8 rows x 2x2 slabs);
    // pairing folds mins to v_min3_f32; no barriers, deep pipeline
    #pragma unroll 2
    for (int j = 0; j < N_PTS; j += 128) {
        float4 qa = cand[j + lane];
        float4 qb = cand[j + 64 + lane];
        #pragma unroll
        for (int k = 0; k < 8; ++k) {
            float sa = fmaf(mx[k], qa.x, fmaf(my[k], qa.y, fmaf(mz[k], qa.z, qa.w)));
            float sb = fmaf(mx[k], qb.x, fmaf(my[k], qb.y, fmaf(mz[k], qb.z, qb.w)));
            bmin[k] = fminf(fminf(bmin[k], sa), sb);
        }
    }

    // full-wave min per row, lane0 sums the wave's 8 rows
    #pragma unroll
    for (int k = 0; k < 8; ++k) {
        #pragma unroll
        for (int d = 1; d < 64; d <<= 1)
            bmin[k] = fminf(bmin[k], __shfl_xor(bmin[k], d, 64));
    }
    if (lane == 0) {
        float val = 0.0f;
        #pragma unroll
        for (int k = 0; k < 8; ++k) {
            // p2 reconstructed: mx=-2px -> p2 = 0.25*(mx^2+my^2+mz^2)
            float p2k = 0.25f * fmaf(mx[k], mx[k], fmaf(my[k], my[k], mz[k] * mz[k]));
            val += sqrtf(fmaxf(bmin[k] + p2k, 0.0f));
        }
        psum[wv] = val;
    }
    __syncthreads();
    if (tid == 0) {
        float ch = psum[0] + psum[1] + psum[2] + psum[3];
        atomicAdd(out, ch * (1.0f / (float)(BATCH * N_PTS)));
    }
}

// ---------------- smooth: barrier-free gated KNN, 16 points/block ----------------
__global__ __launch_bounds__(256, 4) void smooth_kernel(
        const float4* __restrict__ ws, const float* __restrict__ flow,
        float* __restrict__ out) {
    __shared__ float psum[4];
    const int tid = threadIdx.x, bx = blockIdx.x;
    const int lane = tid & 63, wv = tid >> 6;
    const int b  = bx >> 9;
    const int sx = bx & 511;
    const int i0w = sx * 16 + wv * 4;
    const float4* cand = ws + (size_t)(ARR_PC1 + b) * N_PTS;   // packed pc1
    const float* F = flow + (size_t)b * N_PTS * 3;

    float mx[4], my[4], mz[4], p2[4], gr[4];
    unsigned thr[4], o[4][4];
    #pragma unroll
    for (int r = 0; r < 4; ++r) {
        float4 q = cand[i0w + r];            // wave-uniform
        mx[r] = -2.0f * q.x; my[r] = -2.0f * q.y; mz[r] = -2.0f * q.z;
        p2[r] = q.w;
        gr[r] = __builtin_inff();
        thr[r] = 0xFFFFFFFFu;
        #pragma unroll
        for (int k = 0; k < 4; ++k) o[r][k] = 0xFFFFFFFFu;
    }

    // tight thr: per-32-half true top-4 via 5-stage butterfly;
    // bound = max of the two halves' 4th keys (8 distinct real keys >= true 8th)
    auto update_thr = [&]() {
        #pragma unroll
        for (int r = 0; r < 4; ++r) {
            unsigned m0 = o[r][0], m1 = o[r][1], m2 = o[r][2], m3 = o[r][3];
            #pragma unroll
            for (int d = 1; d <= 16; d <<= 1) {
                unsigned q0 = (unsigned)__shfl_xor((int)m0, d, 64);
                unsigned q1 = (unsigned)__shfl_xor((int)m1, d, 64);
                unsigned q2 = (unsigned)__shfl_xor((int)m2, d, 64);
                unsigned q3 = (unsigned)__shfl_xor((int)m3, d, 64);
                unsigned c0 = min(m0, q3), c1 = min(m1, q2);
                unsigned c2 = min(m2, q1), c3 = min(m3, q0);
                ce(c0, c2); ce(c1, c3); ce(c0, c1); ce(c2, c3);
                m0 = c0; m1 = c1; m2 = c2; m3 = c3;
            }
            unsigned bound = max(m3, (unsigned)__shfl_xor((int)m3, 32, 64));
            thr[r] = min(thr[r], bound);
            // +2 truncation-buckets slack: gate passes superset of key<=thr
            float thr_up = __uint_as_float((thr[r] & 0xFFFFE000u) + 0x4000u);
            gr[r] = thr_up - p2[r];
        }
    };

    auto gated_span = [&](int j0, int j1) {
        #pragma unroll 2
        for (int j = j0; j < j1; j += 64) {
            float4 qa = cand[j + lane];
            int jj = j + lane;
            float sc[4];
            #pragma unroll
            for (int r = 0; r < 4; ++r)
                sc[r] = fmaf(mx[r], qa.x, fmaf(my[r], qa.y, fmaf(mz[r], qa.z, qa.w)));
            #pragma unroll
            for (int r = 0; r < 4; ++r) {
                if (__any(sc[r] <= gr[r])) {
                    float d2 = fmaxf(sc[r] + p2[r], 0.0f);
                    unsigned key = (__float_as_uint(d2) & 0xFFFFE000u) | (unsigned)jj;
                    key = (jj == i0w + r) ? 0xFFFFFFFFu : key;
                    insert4(o[r], key);
                }
            }
        }
    };

    // chunk 0 (1024 cands) unconditional sample, then gated spans;
    // thr refresh after 1024 / 2048 / 4096 (same schedule as LDS version)
    #pragma unroll 4
    for (int j = 0; j < 1024; j += 64) {
        float4 qa = cand[j + lane];
        int jj = j + lane;
        #pragma unroll
        for (int r = 0; r < 4; ++r) {
            float ss = fmaf(mx[r], qa.x, fmaf(my[r], qa.y, fmaf(mz[r], qa.z, qa.w)));
            float d2 = fmaxf(ss + p2[r], 0.0f);
            unsigned key = (__float_as_uint(d2) & 0xFFFFE000u) | (unsigned)jj;
            key = (jj == i0w + r) ? 0xFFFFFFFFu : key;
            insert4(o[r], key);
        }
    }
    update_thr();
    gated_span(1024, 2048); update_thr();
    gated_span(2048, 4096); update_thr();
    gated_span(4096, N_PTS);

    // final per-point top-8 + epilogue (sel = (point, k); halves duplicate x2)
    const int sel = lane & 31;
    const int pr = sel >> 3, kk = sel & 7;
    unsigned mykey = 0xFFFFFFFFu;
    #pragma unroll
    for (int r = 0; r < 4; ++r) {
        unsigned m[8] = {o[r][0], o[r][1], o[r][2], o[r][3],
                         0xFFFFFFFFu, 0xFFFFFFFFu, 0xFFFFFFFFu, 0xFFFFFFFFu};
        merge64(m);
        if (pr == r) {
            unsigned k2 = m[0];
            #pragma unroll
            for (int t = 1; t < 8; ++t) k2 = (kk == t) ? m[t] : k2;
            mykey = k2;
        }
    }
    const int i = i0w + pr;
    const int j = (int)(mykey & (N_PTS - 1));
    float dx = F[i*3+0] - F[j*3+0];
    float dy = F[i*3+1] - F[j*3+1];
    float dz = F[i*3+2] - F[j*3+2];
    float sv = sqrtf(fmaf(dx, dx, fmaf(dy, dy, dz * dz)));
    #pragma unroll
    for (int d = 1; d < 64; d <<= 1) sv += __shfl_xor(sv, d, 64);
    if (lane == 0) psum[wv] = sv;
    __syncthreads();

    if (tid == 0) {
        float sm = psum[0] + psum[1] + psum[2] + psum[3];
        // smooth: W=0.5, /2 lane dup
        atomicAdd(out, sm * (0.25f / ((float)BATCH * N_PTS * KNN)));
    }
}

extern "C" void kernel_launch(void* const* d_in, const int* in_sizes, int n_in,
                              void* d_out, int out_size, void* d_ws, size_t ws_size,
                              hipStream_t stream) {
    const float* pc1  = (const float*)d_in[0];
    const float* pc2  = (const float*)d_in[1];
    const float* flow = (const float*)d_in[2];
    float* out = (float*)d_out;
    float4* ws4 = (float4*)d_ws;   // needs 6*8192*16B = 768 KiB

    pack_kernel<<<dim3(6 * N_PTS / 256), 256, 0, stream>>>(pc1, pc2, flow, ws4);
    chamfer_kernel<<<dim3(NBLK_C), 256, 0, stream>>>(ws4, out);
    smooth_kernel<<<dim3(NBLK_S), 256, 0, stream>>>(ws4, flow, out);
}

// Round 5
// 135.761 us; speedup vs baseline: 1.1485x; 1.1485x over previous
//
#include <hip/hip_runtime.h>

#define N_PTS 8192
#define BATCH 2
#define KNN 8
#define NBLK_C 1024                // chamfer: 4 combos x 256 row-blocks (32 rows)
#define NBLK_S 2048                // smooth: 2 batches x 1024 groups (8 points, 2/wave)
#define NBLOCKS (NBLK_C + NBLK_S)  // 3072, role-interleaved by bx%3

// packed workspace layout: float4(x,y,z,|p|^2) per point
//  arr 0,1: pc2[b]            (chamfer candidates dir0 / rows dir1)
//  arr 2,3: pc1[b]+flow[b]    (warped: rows dir0 / candidates dir1)
//  arr 4,5: pc1[b]            (smooth rows+candidates)
// total 6*8192*16B = 768 KiB in d_ws
#define ARR_PC2  0
#define ARR_WARP 2
#define ARR_PC1  4

// ---------------- helpers ----------------
__device__ __forceinline__ void ce(unsigned &x, unsigned &y) {
    unsigned lo = min(x, y), hi = max(x, y); x = lo; y = hi;
}

__device__ __forceinline__ void insert4(unsigned o[4], unsigned key) {
    unsigned n0 = min(o[0], key);
    unsigned n1 = max(o[0], min(o[1], key));
    unsigned n2 = max(o[1], min(o[2], key));
    unsigned n3 = max(o[2], min(o[3], key));
    o[0]=n0; o[1]=n1; o[2]=n2; o[3]=n3;
}

__device__ __forceinline__ void merge_stage8(unsigned m[8], int d) {
    unsigned p[8], c[8];
    #pragma unroll
    for (int k = 0; k < 8; ++k) p[k] = (unsigned)__shfl_xor((int)m[k], d, 64);
    #pragma unroll
    for (int k = 0; k < 8; ++k) c[k] = min(m[k], p[7-k]);
    ce(c[0],c[4]); ce(c[1],c[5]); ce(c[2],c[6]); ce(c[3],c[7]);
    ce(c[0],c[2]); ce(c[1],c[3]); ce(c[4],c[6]); ce(c[5],c[7]);
    ce(c[0],c[1]); ce(c[2],c[3]); ce(c[4],c[5]); ce(c[6],c[7]);
    #pragma unroll
    for (int k = 0; k < 8; ++k) m[k] = c[k];
}

__device__ __forceinline__ void merge64(unsigned m[8]) {
    merge_stage8(m, 1); merge_stage8(m, 2); merge_stage8(m, 4);
    merge_stage8(m, 8); merge_stage8(m, 16); merge_stage8(m, 32);
}

// ---------------- pack: 6 float4 arrays, one-time warp-add + |p|^2 ----------------
__global__ __launch_bounds__(256) void pack_kernel(
        const float* __restrict__ pc1, const float* __restrict__ pc2,
        const float* __restrict__ flow, float4* __restrict__ ws) {
    const int t = blockIdx.x * 256 + threadIdx.x;   // 0 .. 6*8192-1
    const int arr = t >> 13, i = t & (N_PTS - 1);
    const int bb = arr & 1;
    const size_t base = (size_t)bb * N_PTS * 3 + (size_t)i * 3;
    float x, y, z;
    if (arr < 2)      { x = pc2[base+0];              y = pc2[base+1];              z = pc2[base+2]; }
    else if (arr < 4) { x = pc1[base+0] + flow[base+0];
                        y = pc1[base+1] + flow[base+1];
                        z = pc1[base+2] + flow[base+2]; }
    else              { x = pc1[base+0];              y = pc1[base+1];              z = pc1[base+2]; }
    ws[t] = make_float4(x, y, z, fmaf(x, x, fmaf(y, y, z * z)));
}

// ---------------- mega: role-interleaved C|S blocks, barrier-free scans ----------------
// R4 ablation: smooth = 72us (the pole), chamfer ~28, pack ~3; split serialized
// them (156 total). Smooth was latency-bound, wave-count-capped: 16384 pts /
// 4 rows/wave = 4096 waves = 50% occupancy HARD cap (36% meas), chain-heavy
// code (insert nets, shfl butterflies, 4 branches/64 cands) can't fill a SIMD
// at 3-4 waves. R5: (a) 2 rows/wave -> 8192 S-waves = 100% occupancy ceiling;
// (b) paired 128-cand slabs, 1 __any gate per row-pair (2 branches/128 vs 8);
// (c) re-fused single dispatch, role = bx%3 (2 S + 1 C per triple): chamfer's
// dense independent FMA fills smooth's latency bubbles on the same SIMD.
// launch_bounds(256,4): 128-VGPR no-spill (R1 lesson); both roles <=~56 VGPR
// -> 8 blocks/CU natural.
__global__ __launch_bounds__(256, 4) void mega_kernel(
        const float4* __restrict__ ws, const float* __restrict__ flow,
        float* __restrict__ out) {
    __shared__ float psum[4];
    const int tid = threadIdx.x, bx = blockIdx.x;
    const int lane = tid & 63, wv = tid >> 6;
    const int ri = bx / 3, role = bx % 3;   // ri in [0,1024)

    if (role == 2) {
        // ============ role C: chamfer, 32 rows/block (8/thread), full scan ============
        const int z = ri >> 8, bb = z & 1, dir = z >> 1;
        const int cb = ri & 255;
        const float4* rows = ws + (size_t)((dir == 0 ? ARR_WARP : ARR_PC2) + bb) * N_PTS;
        const float4* cand = ws + (size_t)((dir == 0 ? ARR_PC2 : ARR_WARP) + bb) * N_PTS;
        const int rbase = cb * 32 + wv * 8;      // wave-uniform 8-row group

        float mx[8], my[8], mz[8], bmin[8];
        #pragma unroll
        for (int k = 0; k < 8; ++k) {
            float4 q = rows[rbase + k];          // wave-uniform -> broadcast load
            mx[k] = -2.0f * q.x; my[k] = -2.0f * q.y; mz[k] = -2.0f * q.z;
            bmin[k] = __builtin_inff();
        }

        // 64 paired iters: 2 dwordx4 feed 32 evals; mins fold to v_min3_f32
        #pragma unroll 2
        for (int j = 0; j < N_PTS; j += 128) {
            float4 qa = cand[j + lane];
            float4 qb = cand[j + 64 + lane];
            #pragma unroll
            for (int k = 0; k < 8; ++k) {
                float sa = fmaf(mx[k], qa.x, fmaf(my[k], qa.y, fmaf(mz[k], qa.z, qa.w)));
                float sb = fmaf(mx[k], qb.x, fmaf(my[k], qb.y, fmaf(mz[k], qb.z, qb.w)));
                bmin[k] = fminf(fminf(bmin[k], sa), sb);
            }
        }

        #pragma unroll
        for (int k = 0; k < 8; ++k) {
            #pragma unroll
            for (int d = 1; d < 64; d <<= 1)
                bmin[k] = fminf(bmin[k], __shfl_xor(bmin[k], d, 64));
        }
        if (lane == 0) {
            float val = 0.0f;
            #pragma unroll
            for (int k = 0; k < 8; ++k) {
                // p2 reconstructed: mx=-2px -> p2 = 0.25*(mx^2+my^2+mz^2)
                float p2k = 0.25f * fmaf(mx[k], mx[k], fmaf(my[k], my[k], mz[k] * mz[k]));
                val += sqrtf(fmaxf(bmin[k] + p2k, 0.0f));
            }
            psum[wv] = val;
        }
        __syncthreads();
        if (tid == 0) {
            float ch = psum[0] + psum[1] + psum[2] + psum[3];
            atomicAdd(out, ch * (1.0f / (float)(BATCH * N_PTS)));
        }
    } else {
        // ============ role S: smooth, 8 points/block (2/wave), gated KNN ============
        const int sbx = ri * 2 + role;           // [0, 2048)
        const int b  = sbx >> 10;
        const int sx = sbx & 1023;
        const int i0w = sx * 8 + wv * 2;
        const float4* cand = ws + (size_t)(ARR_PC1 + b) * N_PTS;
        const float* F = flow + (size_t)b * N_PTS * 3;

        float mx[2], my[2], mz[2], p2[2], gr[2];
        unsigned thr[2], o[2][4];
        #pragma unroll
        for (int r = 0; r < 2; ++r) {
            float4 q = cand[i0w + r];            // wave-uniform
            mx[r] = -2.0f * q.x; my[r] = -2.0f * q.y; mz[r] = -2.0f * q.z;
            p2[r] = q.w;
            gr[r] = __builtin_inff();
            thr[r] = 0xFFFFFFFFu;
            #pragma unroll
            for (int k = 0; k < 4; ++k) o[r][k] = 0xFFFFFFFFu;
        }

        // tight thr: per-32-half true top-4 via 5-stage butterfly;
        // bound = max of the two halves' 4th keys (8 real keys >= true 8th)
        auto update_thr = [&]() {
            #pragma unroll
            for (int r = 0; r < 2; ++r) {
                unsigned m0 = o[r][0], m1 = o[r][1], m2 = o[r][2], m3 = o[r][3];
                #pragma unroll
                for (int d = 1; d <= 16; d <<= 1) {
                    unsigned q0 = (unsigned)__shfl_xor((int)m0, d, 64);
                    unsigned q1 = (unsigned)__shfl_xor((int)m1, d, 64);
                    unsigned q2 = (unsigned)__shfl_xor((int)m2, d, 64);
                    unsigned q3 = (unsigned)__shfl_xor((int)m3, d, 64);
                    unsigned c0 = min(m0, q3), c1 = min(m1, q2);
                    unsigned c2 = min(m2, q1), c3 = min(m3, q0);
                    ce(c0, c2); ce(c1, c3); ce(c0, c1); ce(c2, c3);
                    m0 = c0; m1 = c1; m2 = c2; m3 = c3;
                }
                unsigned bound = max(m3, (unsigned)__shfl_xor((int)m3, 32, 64));
                thr[r] = min(thr[r], bound);
                // +2 truncation-buckets slack: gate passes superset of key<=thr
                float thr_up = __uint_as_float((thr[r] & 0xFFFFE000u) + 0x4000u);
                gr[r] = thr_up - p2[r];
            }
        };

        // paired slabs: 2 loads in flight, ONE uniform branch per row per 128 cands
        auto gated_span = [&](int j0, int j1) {
            #pragma unroll 2
            for (int j = j0; j < j1; j += 128) {
                float4 qa = cand[j + lane];
                float4 qb = cand[j + 64 + lane];
                int ja = j + lane, jb = j + 64 + lane;
                float sa[2], sb[2];
                #pragma unroll
                for (int r = 0; r < 2; ++r) {
                    sa[r] = fmaf(mx[r], qa.x, fmaf(my[r], qa.y, fmaf(mz[r], qa.z, qa.w)));
                    sb[r] = fmaf(mx[r], qb.x, fmaf(my[r], qb.y, fmaf(mz[r], qb.z, qb.w)));
                }
                #pragma unroll
                for (int r = 0; r < 2; ++r) {
                    if (__any(fminf(sa[r], sb[r]) <= gr[r])) {
                        float da = fmaxf(sa[r] + p2[r], 0.0f);
                        unsigned ka = (__float_as_uint(da) & 0xFFFFE000u) | (unsigned)ja;
                        ka = (ja == i0w + r) ? 0xFFFFFFFFu : ka;
                        insert4(o[r], ka);
                        float db = fmaxf(sb[r] + p2[r], 0.0f);
                        unsigned kb = (__float_as_uint(db) & 0xFFFFE000u) | (unsigned)jb;
                        kb = (jb == i0w + r) ? 0xFFFFFFFFu : kb;
                        insert4(o[r], kb);
                    }
                }
            }
        };

        // chunk 0 (1024 cands) unconditional sample, then gated spans;
        // thr refresh after 1024 / 2048 / 4096 (proven schedule)
        #pragma unroll 2
        for (int j = 0; j < 1024; j += 128) {
            float4 qa = cand[j + lane];
            float4 qb = cand[j + 64 + lane];
            int ja = j + lane, jb = j + 64 + lane;
            #pragma unroll
            for (int r = 0; r < 2; ++r) {
                float sa = fmaf(mx[r], qa.x, fmaf(my[r], qa.y, fmaf(mz[r], qa.z, qa.w)));
                float da = fmaxf(sa + p2[r], 0.0f);
                unsigned ka = (__float_as_uint(da) & 0xFFFFE000u) | (unsigned)ja;
                ka = (ja == i0w + r) ? 0xFFFFFFFFu : ka;
                insert4(o[r], ka);
                float sb = fmaf(mx[r], qb.x, fmaf(my[r], qb.y, fmaf(mz[r], qb.z, qb.w)));
                float db = fmaxf(sb + p2[r], 0.0f);
                unsigned kb = (__float_as_uint(db) & 0xFFFFE000u) | (unsigned)jb;
                kb = (jb == i0w + r) ? 0xFFFFFFFFu : kb;
                insert4(o[r], kb);
            }
        }
        update_thr();
        gated_span(1024, 2048); update_thr();
        gated_span(2048, 4096); update_thr();
        gated_span(4096, N_PTS);

        // final per-point top-8 + epilogue; sel = (point, k) over 16 slots,
        // lane dup x4 -> scale /4
        const int sel = lane & 15;
        const int pr = sel >> 3, kk = sel & 7;
        unsigned mykey = 0xFFFFFFFFu;
        #pragma unroll
        for (int r = 0; r < 2; ++r) {
            unsigned m[8] = {o[r][0], o[r][1], o[r][2], o[r][3],
                             0xFFFFFFFFu, 0xFFFFFFFFu, 0xFFFFFFFFu, 0xFFFFFFFFu};
            merge64(m);
            if (pr == r) {
                unsigned k2 = m[0];
                #pragma unroll
                for (int t = 1; t < 8; ++t) k2 = (kk == t) ? m[t] : k2;
                mykey = k2;
            }
        }
        const int i = i0w + pr;
        const int j = (int)(mykey & (N_PTS - 1));
        float dx = F[i*3+0] - F[j*3+0];
        float dy = F[i*3+1] - F[j*3+1];
        float dz = F[i*3+2] - F[j*3+2];
        float sv = sqrtf(fmaf(dx, dx, fmaf(dy, dy, dz * dz)));
        #pragma unroll
        for (int d = 1; d < 64; d <<= 1) sv += __shfl_xor(sv, d, 64);
        if (lane == 0) psum[wv] = sv;
        __syncthreads();

        if (tid == 0) {
            float sm = psum[0] + psum[1] + psum[2] + psum[3];
            // smooth: W=0.5, /4 lane dup -> 0.125
            atomicAdd(out, sm * (0.125f / ((float)BATCH * N_PTS * KNN)));
        }
    }
}

extern "C" void kernel_launch(void* const* d_in, const int* in_sizes, int n_in,
                              void* d_out, int out_size, void* d_ws, size_t ws_size,
                              hipStream_t stream) {
    const float* pc1  = (const float*)d_in[0];
    const float* pc2  = (const float*)d_in[1];
    const float* flow = (const float*)d_in[2];
    float* out = (float*)d_out;
    float4* ws4 = (float4*)d_ws;   // needs 6*8192*16B = 768 KiB

    pack_kernel<<<dim3(6 * N_PTS / 256), 256, 0, stream>>>(pc1, pc2, flow, ws4);
    mega_kernel<<<dim3(NBLOCKS), 256, 0, stream>>>(ws4, flow, out);
}